// Round 3
// baseline (968.549 us; speedup 1.0000x reference)
//
#include <hip/hip_runtime.h>
#include <hip/hip_bf16.h>
#include <cstdint>

#define NTOK 4096
#define DMODEL 2048
#define NEXP 8
#define HR 1408
#define HSHARED 2816
#define MAXT128 72

typedef __attribute__((ext_vector_type(8))) short bf16x8;
typedef __attribute__((ext_vector_type(4))) float f32x4;

__device__ inline unsigned short f2b(float f) {
    unsigned u = __float_as_uint(f);
    u += 0x7fffu + ((u >> 16) & 1u);   // RNE
    return (unsigned short)(u >> 16);
}
__device__ inline unsigned pack2(float a, float b) {
    return (unsigned)f2b(a) | ((unsigned)f2b(b) << 16);
}

// async global->LDS, 16B per lane; dest = lds(wave-uniform) + lane*16
__device__ __forceinline__ void gll16(unsigned short* lds, const unsigned short* g) {
    __builtin_amdgcn_global_load_lds(
        (__attribute__((address_space(1))) void*)g,
        (__attribute__((address_space(3))) void*)lds, 16, 0, 0);
}

// ------------- Router (fused x fp32->bf16 cvt): 2 tokens/wave -------------
__global__ __launch_bounds__(256) void k_router2(const float* __restrict__ x,
                                                 const float* __restrict__ rw,
                                                 unsigned short* __restrict__ xb,
                                                 int* __restrict__ topi,
                                                 float* __restrict__ topw,
                                                 int* __restrict__ counts) {
    __shared__ float rws[NEXP * DMODEL];   // 64 KB
    int tid = threadIdx.x;
    for (int i = tid * 4; i < NEXP * DMODEL; i += 1024)
        *(float4*)&rws[i] = *(const float4*)&rw[i];
    __syncthreads();
    int wv = tid >> 6, lane = tid & 63;
#pragma unroll
    for (int tk = 0; tk < 2; tk++) {
        int tok = blockIdx.x * 8 + wv * 2 + tk;
        const float* xr = x + (size_t)tok * DMODEL;
        unsigned short* xbr = xb + (size_t)tok * DMODEL;
        float s[NEXP] = {0.f,0.f,0.f,0.f,0.f,0.f,0.f,0.f};
#pragma unroll
        for (int i = 0; i < 8; i++) {
            int d = i * 256 + lane * 4;
            float4 xv = *(const float4*)(xr + d);
            uint2 p; p.x = pack2(xv.x, xv.y); p.y = pack2(xv.z, xv.w);
            *(uint2*)(xbr + d) = p;
#pragma unroll
            for (int e = 0; e < NEXP; e++) {
                float4 w = *(const float4*)&rws[e * DMODEL + d];
                s[e] = fmaf(xv.x, w.x, s[e]); s[e] = fmaf(xv.y, w.y, s[e]);
                s[e] = fmaf(xv.z, w.z, s[e]); s[e] = fmaf(xv.w, w.w, s[e]);
            }
        }
#pragma unroll
        for (int e = 0; e < NEXP; e++)
#pragma unroll
            for (int o = 32; o > 0; o >>= 1) s[e] += __shfl_xor(s[e], o, 64);
        if (lane == 0) {
            int i1 = 0;
#pragma unroll
            for (int e = 1; e < NEXP; e++) if (s[e] > s[i1]) i1 = e;
            int i2 = (i1 == 0) ? 1 : 0;
#pragma unroll
            for (int e = 0; e < NEXP; e++) if (e != i1 && s[e] > s[i2]) i2 = e;
            float mx = s[0];
#pragma unroll
            for (int e = 1; e < NEXP; e++) mx = fmaxf(mx, s[e]);
            float den = 0.f, ex[NEXP];
#pragma unroll
            for (int e = 0; e < NEXP; e++) { ex[e] = __expf(s[e] - mx); den += ex[e]; }
            float v1 = ex[i1] / den, v2 = ex[i2] / den;
            float inv = 1.f / (v1 + v2 + 1e-20f);
            topi[2 * tok] = i1; topi[2 * tok + 1] = i2;
            topw[2 * tok] = v1 * inv; topw[2 * tok + 1] = v2 * inv;
            atomicAdd(&counts[i1], 1); atomicAdd(&counts[i2], 1);
        }
    }
}

__global__ void k_scan(int* counts, int* offsets, int* cursors, int* ntiles,
                       int* tile_e, int* tile_r, int step) {
    if (threadIdx.x == 0 && blockIdx.x == 0) {
        int off = 0, nt = 0;
        for (int e = 0; e < NEXP; e++) {
            offsets[e] = off; cursors[e] = off;
            int c = counts[e];
            for (int r = 0; r < c; r += step) { tile_e[nt] = e; tile_r[nt] = r; nt++; }
            off += c;
        }
        ntiles[0] = nt;
    }
}

__global__ __launch_bounds__(256) void k_fill(const int* __restrict__ topi,
                                              const float* __restrict__ topw,
                                              int* cursors, int* at, float* aw) {
    int t = blockIdx.x * 256 + threadIdx.x;
    if (t >= NTOK) return;
#pragma unroll
    for (int k = 0; k < 2; k++) {
        int e = topi[2 * t + k];
        int pos = atomicAdd(&cursors[e], 1);
        at[pos] = t; aw[pos] = topw[2 * t + k];
    }
}

// ------------- fp32 [K,N] -> bf16 [N,dstride-major] transpose-convert -------
__device__ __forceinline__ void tcvt_tile(const float* __restrict__ src,
                                          unsigned short* __restrict__ dst,
                                          int N, int dstride, int n0, int k0) {
    __shared__ unsigned short T[64][72];
    int t = threadIdx.x;
    int kr = t >> 4, nc = (t & 15) * 4;
#pragma unroll
    for (int i = 0; i < 4; i++) {
        int k = kr + i * 16;
        float4 v = *(const float4*)(src + (size_t)(k0 + k) * N + n0 + nc);
        T[k][nc] = f2b(v.x); T[k][nc + 1] = f2b(v.y);
        T[k][nc + 2] = f2b(v.z); T[k][nc + 3] = f2b(v.w);
    }
    __syncthreads();
    int nr = t >> 3, kc = (t & 7) * 8;
#pragma unroll
    for (int j = 0; j < 2; j++) {
        int n = nr + j * 32;
        unsigned short tmp[8];
#pragma unroll
        for (int u = 0; u < 8; u++) tmp[u] = T[kc + u][n];
        *(uint4*)(dst + (size_t)(n0 + n) * dstride + k0 + kc) = *(uint4*)tmp;
    }
}

// z<8: wg expert z ; z>=8: wu expert z-8.  [2048,1408] -> [1408,2048]
__global__ __launch_bounds__(256) void k_tcvt_gu(const float* __restrict__ wg,
                                                 const float* __restrict__ wu,
                                                 unsigned short* __restrict__ wgT,
                                                 unsigned short* __restrict__ wuT) {
    int z = blockIdx.z;
    const float* src = (z < 8 ? wg : wu) + (size_t)(z & 7) * DMODEL * HR;
    unsigned short* dst = (z < 8 ? wgT : wuT) + (size_t)(z & 7) * HR * DMODEL;
    tcvt_tile(src, dst, HR, DMODEL, blockIdx.x * 64, blockIdx.y * 64);
}

// z=0: sg, z=1: su.  [2048,2816] -> [2816,2048]
__global__ __launch_bounds__(256) void k_tcvt_s(const float* __restrict__ sg,
                                                const float* __restrict__ su,
                                                unsigned short* __restrict__ sgT,
                                                unsigned short* __restrict__ suT) {
    int z = blockIdx.z;
    tcvt_tile(z ? su : sg, z ? suT : sgT, HSHARED, DMODEL,
              blockIdx.x * 64, blockIdx.y * 64);
}

// z<8: wd expert z [1408,2048]->[2048,1408]; z=8,9: sd K-halves [2816,2048]->[2048,2816]
__global__ __launch_bounds__(256) void k_tcvt_d(const float* __restrict__ wd,
                                                const float* __restrict__ sd,
                                                unsigned short* __restrict__ wdT,
                                                unsigned short* __restrict__ sdT) {
    int z = blockIdx.z;
    const float* src;
    unsigned short* dst;
    int dstride;
    if (z < 8) {
        src = wd + (size_t)z * HR * DMODEL;
        dst = wdT + (size_t)z * DMODEL * HR;
        dstride = HR;
    } else {
        src = sd + (size_t)(z - 8) * HR * DMODEL;
        dst = sdT + (size_t)(z - 8) * HR;
        dstride = HSHARED;
    }
    tcvt_tile(src, dst, DMODEL, dstride, blockIdx.x * 64, blockIdx.y * 64);
}

// ============== merged gate/up GEMM: shared + routed in one dispatch =========
// BM=128, BN=64 (each of g,u), BK=64, K=2048 for all jobs.
#define GU_SH_JOBS 1408   // 32 m-blocks * 44 n-blocks
#define GU_RT_NB   22     // HR/64
__global__ __launch_bounds__(256) void kg_all(
    const unsigned short* __restrict__ xb,
    const unsigned short* __restrict__ sgT, const unsigned short* __restrict__ suT,
    const unsigned short* __restrict__ wgT, const unsigned short* __restrict__ wuT,
    const int* __restrict__ tile_e, const int* __restrict__ tile_r,
    const int* __restrict__ offsets, const int* __restrict__ counts,
    const int* __restrict__ ntiles, const int* __restrict__ at,
    unsigned short* __restrict__ h_s, unsigned short* __restrict__ h_r) {
    int j = blockIdx.x;
    int m0, mcnt, n0, Hld;
    const unsigned short *Bg, *Bu;
    unsigned short* ho;
    bool gath;
    if (j < GU_SH_JOBS) {
        gath = false;
        m0 = (j / 44) * 128; mcnt = 128;
        n0 = (j % 44) * 64;
        Bg = sgT; Bu = suT; Hld = HSHARED; ho = h_s;
    } else {
        j -= GU_SH_JOBS;
        int tile = j / GU_RT_NB;
        if (tile >= ntiles[0]) return;
        gath = true;
        n0 = (j % GU_RT_NB) * 64;
        int e = tile_e[tile], ro = tile_r[tile];
        m0 = offsets[e] + ro;
        mcnt = counts[e] - ro; if (mcnt > 128) mcnt = 128;
        size_t wo = (size_t)e * HR * DMODEL;
        Bg = wgT + wo; Bu = wuT + wo; Hld = HR; ho = h_r;
    }

    __shared__ __align__(16) unsigned short As[128 * 64];
    __shared__ __align__(16) unsigned short Bgs[64 * 64];
    __shared__ __align__(16) unsigned short Bus[64 * 64];

    int tid = threadIdx.x;
    int wv = tid >> 6, lane = tid & 63;
    int rbase = tid >> 3;
    int kc = (tid & 7) ^ ((tid >> 3) & 7);   // XOR-swizzled chunk (conflict-free)
    const unsigned short* arp[4];
#pragma unroll
    for (int j2 = 0; j2 < 4; j2++) {
        int row = j2 * 32 + rbase;
        int cl = row < mcnt ? row : mcnt - 1;
        int grow = gath ? at[m0 + cl] : (m0 + cl);
        arp[j2] = xb + (size_t)grow * DMODEL + kc * 8;
    }
    const unsigned short* bgp[2];
    const unsigned short* bup[2];
#pragma unroll
    for (int j2 = 0; j2 < 2; j2++) {
        int row = j2 * 32 + rbase;
        bgp[j2] = Bg + (size_t)(n0 + row) * DMODEL + kc * 8;
        bup[j2] = Bu + (size_t)(n0 + row) * DMODEL + kc * 8;
    }
    unsigned short* a_l = As + (wv << 6) * 8;
    unsigned short* g_l = Bgs + (wv << 6) * 8;
    unsigned short* u_l = Bus + (wv << 6) * 8;

    int fr = lane & 15, quad = lane >> 4, sw = fr & 7;
    int wm = (wv & 1) << 6, wn = (wv >> 1) << 5;

    f32x4 accg[4][2] = {};
    f32x4 accu[4][2] = {};

    for (int k0 = 0; k0 < DMODEL; k0 += 64) {
        __syncthreads();
#pragma unroll
        for (int j2 = 0; j2 < 4; j2++) gll16(a_l + j2 * 2048, arp[j2] + k0);
#pragma unroll
        for (int j2 = 0; j2 < 2; j2++) {
            gll16(g_l + j2 * 2048, bgp[j2] + k0);
            gll16(u_l + j2 * 2048, bup[j2] + k0);
        }
        __syncthreads();
#pragma unroll
        for (int s = 0; s < 2; s++) {
            int off = (((s << 2) + quad) ^ sw) << 3;
            bf16x8 a[4], g[2], u[2];
#pragma unroll
            for (int tm = 0; tm < 4; tm++)
                a[tm] = *(const bf16x8*)&As[(wm + tm * 16 + fr) * 64 + off];
#pragma unroll
            for (int tn = 0; tn < 2; tn++) {
                int rb = (wn + tn * 16 + fr) * 64 + off;
                g[tn] = *(const bf16x8*)&Bgs[rb];
                u[tn] = *(const bf16x8*)&Bus[rb];
            }
#pragma unroll
            for (int tm = 0; tm < 4; tm++)
#pragma unroll
                for (int tn = 0; tn < 2; tn++) {
                    accg[tm][tn] = __builtin_amdgcn_mfma_f32_16x16x32_bf16(a[tm], g[tn], accg[tm][tn], 0, 0, 0);
                    accu[tm][tn] = __builtin_amdgcn_mfma_f32_16x16x32_bf16(a[tm], u[tn], accu[tm][tn], 0, 0, 0);
                }
        }
    }
#pragma unroll
    for (int tm = 0; tm < 4; tm++)
#pragma unroll
        for (int r = 0; r < 4; r++) {
            int row = wm + tm * 16 + (quad << 2) + r;
            if (row < mcnt) {
#pragma unroll
                for (int tn = 0; tn < 2; tn++) {
                    float gv = accg[tm][tn][r], uv = accu[tm][tn][r];
                    float hv = (gv / (1.f + __expf(-gv))) * uv;
                    ho[(size_t)(m0 + row) * Hld + n0 + wn + tn * 16 + fr] = f2b(hv);
                }
            }
        }
}

// ============== merged down GEMM: shared + routed, atomic epilogue ==========
// BM=128, BN=128, BK=64; out pre-zeroed.
#define DN_SH_JOBS 512   // 32 m-blocks * 16 n-blocks
__global__ __launch_bounds__(256) void kd_all(
    const unsigned short* __restrict__ h_s, const unsigned short* __restrict__ h_r,
    const unsigned short* __restrict__ sdT, const unsigned short* __restrict__ wdT,
    const int* __restrict__ tile_e, const int* __restrict__ tile_r,
    const int* __restrict__ offsets, const int* __restrict__ counts,
    const int* __restrict__ ntiles, const int* __restrict__ at,
    const float* __restrict__ aw, float* __restrict__ out) {
    int j = blockIdx.x;
    int m0, mcnt, n0, Kd;
    const unsigned short *Ab, *Bb;
    bool gath;
    if (j < DN_SH_JOBS) {
        gath = false;
        m0 = (j >> 4) * 128; mcnt = 128;
        n0 = (j & 15) * 128;
        Ab = h_s; Bb = sdT; Kd = HSHARED;
    } else {
        j -= DN_SH_JOBS;
        int tile = j >> 4;
        if (tile >= ntiles[0]) return;
        gath = true;
        n0 = (j & 15) * 128;
        int e = tile_e[tile], ro = tile_r[tile];
        m0 = offsets[e] + ro;
        mcnt = counts[e] - ro; if (mcnt > 128) mcnt = 128;
        Ab = h_r; Bb = wdT + (size_t)e * DMODEL * HR;
        Kd = HR;
    }

    __shared__ __align__(16) unsigned short As[128 * 64];
    __shared__ __align__(16) unsigned short Bs[128 * 64];

    int tid = threadIdx.x;
    int wv = tid >> 6, lane = tid & 63;
    int rbase = tid >> 3;
    int kc = (tid & 7) ^ ((tid >> 3) & 7);
    const unsigned short* arp[4];
    const unsigned short* brp[4];
#pragma unroll
    for (int j2 = 0; j2 < 4; j2++) {
        int row = j2 * 32 + rbase;
        int cl = row < mcnt ? row : mcnt - 1;
        arp[j2] = Ab + (size_t)(m0 + cl) * Kd + kc * 8;
        brp[j2] = Bb + (size_t)(n0 + row) * Kd + kc * 8;
    }
    unsigned short* a_l = As + (wv << 6) * 8;
    unsigned short* b_l = Bs + (wv << 6) * 8;

    int fr = lane & 15, quad = lane >> 4, sw = fr & 7;
    int wm = (wv & 1) << 6, wn = (wv >> 1) << 6;

    f32x4 acc[4][4] = {};

    for (int k0 = 0; k0 < Kd; k0 += 64) {
        __syncthreads();
#pragma unroll
        for (int j2 = 0; j2 < 4; j2++) {
            gll16(a_l + j2 * 2048, arp[j2] + k0);
            gll16(b_l + j2 * 2048, brp[j2] + k0);
        }
        __syncthreads();
#pragma unroll
        for (int s = 0; s < 2; s++) {
            int off = (((s << 2) + quad) ^ sw) << 3;
            bf16x8 a[4], b[4];
#pragma unroll
            for (int tm = 0; tm < 4; tm++)
                a[tm] = *(const bf16x8*)&As[(wm + tm * 16 + fr) * 64 + off];
#pragma unroll
            for (int tn = 0; tn < 4; tn++)
                b[tn] = *(const bf16x8*)&Bs[(wn + tn * 16 + fr) * 64 + off];
#pragma unroll
            for (int tm = 0; tm < 4; tm++)
#pragma unroll
                for (int tn = 0; tn < 4; tn++)
                    acc[tm][tn] = __builtin_amdgcn_mfma_f32_16x16x32_bf16(a[tm], b[tn], acc[tm][tn], 0, 0, 0);
        }
    }
#pragma unroll
    for (int tm = 0; tm < 4; tm++)
#pragma unroll
        for (int r = 0; r < 4; r++) {
            int row = wm + tm * 16 + (quad << 2) + r;
            if (row < mcnt) {
                int tok; float w;
                if (gath) { tok = at[m0 + row]; w = aw[m0 + row]; }
                else      { tok = m0 + row;     w = 1.f; }
#pragma unroll
                for (int tn = 0; tn < 4; tn++)
                    atomicAdd(&out[(size_t)tok * DMODEL + n0 + wn + tn * 16 + fr],
                              w * acc[tm][tn][r]);
            }
        }
}

// ============ T1 kernels (round-2 proven two-phase fast path) ================
template <bool GATHERED>
__global__ __launch_bounds__(256) void kf_gateup(
    const unsigned short* __restrict__ xb, const unsigned short* __restrict__ BgT,
    const unsigned short* __restrict__ BuT, int K, int Hld, int ebase,
    const int* __restrict__ tile_e, const int* __restrict__ tile_r,
    const int* __restrict__ offsets, const int* __restrict__ counts,
    const int* __restrict__ ntiles, const int* __restrict__ at,
    unsigned short* __restrict__ hout) {
    int m0, mcnt;
    const unsigned short* bgw = BgT;
    const unsigned short* buw = BuT;
    if (GATHERED) {
        if ((int)blockIdx.x >= ntiles[0]) return;
        int e = tile_e[blockIdx.x];
        if (e < ebase || e >= ebase + 4) return;
        int ro = tile_r[blockIdx.x];
        m0 = offsets[e] + ro;
        mcnt = counts[e] - ro; if (mcnt > 128) mcnt = 128;
        size_t wofs = (size_t)(e - ebase) * Hld * K;
        bgw += wofs; buw += wofs;
    } else { m0 = blockIdx.x * 128; mcnt = 128; }
    int n0 = blockIdx.y * 64;
    __shared__ __align__(16) unsigned short As[128 * 64];
    __shared__ __align__(16) unsigned short Bgs[64 * 64];
    __shared__ __align__(16) unsigned short Bus[64 * 64];
    int tid = threadIdx.x;
    int wv = tid >> 6, lane = tid & 63;
    int rbase = tid >> 3;
    int kc = (tid & 7) ^ ((tid >> 3) & 7);
    const unsigned short* arp[4];
#pragma unroll
    for (int j = 0; j < 4; j++) {
        int row = j * 32 + rbase;
        int cl = row < mcnt ? row : mcnt - 1;
        int grow = GATHERED ? at[m0 + cl] : (m0 + cl);
        arp[j] = xb + (size_t)grow * K + kc * 8;
    }
    const unsigned short* bgp[2];
    const unsigned short* bup[2];
#pragma unroll
    for (int j = 0; j < 2; j++) {
        int row = j * 32 + rbase;
        bgp[j] = bgw + (size_t)(n0 + row) * K + kc * 8;
        bup[j] = buw + (size_t)(n0 + row) * K + kc * 8;
    }
    unsigned short* a_l = As + (wv << 6) * 8;
    unsigned short* g_l = Bgs + (wv << 6) * 8;
    unsigned short* u_l = Bus + (wv << 6) * 8;
    int fr = lane & 15, quad = lane >> 4, sw = fr & 7;
    int wm = (wv & 1) << 6, wn = (wv >> 1) << 5;
    f32x4 accg[4][2] = {};
    f32x4 accu[4][2] = {};
    for (int k0 = 0; k0 < K; k0 += 64) {
        __syncthreads();
#pragma unroll
        for (int j = 0; j < 4; j++) gll16(a_l + j * 2048, arp[j] + k0);
#pragma unroll
        for (int j = 0; j < 2; j++) {
            gll16(g_l + j * 2048, bgp[j] + k0);
            gll16(u_l + j * 2048, bup[j] + k0);
        }
        __syncthreads();
#pragma unroll
        for (int s = 0; s < 2; s++) {
            int off = (((s << 2) + quad) ^ sw) << 3;
            bf16x8 a[4], g[2], u[2];
#pragma unroll
            for (int tm = 0; tm < 4; tm++)
                a[tm] = *(const bf16x8*)&As[(wm + tm * 16 + fr) * 64 + off];
#pragma unroll
            for (int tn = 0; tn < 2; tn++) {
                int rb = (wn + tn * 16 + fr) * 64 + off;
                g[tn] = *(const bf16x8*)&Bgs[rb];
                u[tn] = *(const bf16x8*)&Bus[rb];
            }
#pragma unroll
            for (int tm = 0; tm < 4; tm++)
#pragma unroll
                for (int tn = 0; tn < 2; tn++) {
                    accg[tm][tn] = __builtin_amdgcn_mfma_f32_16x16x32_bf16(a[tm], g[tn], accg[tm][tn], 0, 0, 0);
                    accu[tm][tn] = __builtin_amdgcn_mfma_f32_16x16x32_bf16(a[tm], u[tn], accu[tm][tn], 0, 0, 0);
                }
        }
    }
#pragma unroll
    for (int tm = 0; tm < 4; tm++)
#pragma unroll
        for (int r = 0; r < 4; r++) {
            int row = wm + tm * 16 + (quad << 2) + r;
            if (row < mcnt) {
#pragma unroll
                for (int tn = 0; tn < 2; tn++) {
                    float gv = accg[tm][tn][r], uv = accu[tm][tn][r];
                    float hv = (gv / (1.f + __expf(-gv))) * uv;
                    hout[(size_t)(m0 + row) * Hld + n0 + wn + tn * 16 + fr] = f2b(hv);
                }
            }
        }
}

template <bool GATHERED>
__global__ __launch_bounds__(256) void kf_down(
    const unsigned short* __restrict__ h, const unsigned short* __restrict__ BT,
    int K,
    const int* __restrict__ tile_e, const int* __restrict__ tile_r,
    const int* __restrict__ offsets, const int* __restrict__ counts,
    const int* __restrict__ ntiles, const int* __restrict__ at,
    const float* __restrict__ awt, float* __restrict__ out) {
    int m0, mcnt;
    const unsigned short* bw = BT;
    if (GATHERED) {
        if ((int)blockIdx.x >= ntiles[0]) return;
        int e = tile_e[blockIdx.x], ro = tile_r[blockIdx.x];
        m0 = offsets[e] + ro;
        mcnt = counts[e] - ro; if (mcnt > 128) mcnt = 128;
        bw += (size_t)e * DMODEL * K;
    } else { m0 = blockIdx.x * 128; mcnt = 128; }
    int n0 = blockIdx.y * 128;
    __shared__ __align__(16) unsigned short As[128 * 64];
    __shared__ __align__(16) unsigned short Bs[128 * 64];
    int tid = threadIdx.x;
    int wv = tid >> 6, lane = tid & 63;
    int rbase = tid >> 3;
    int kc = (tid & 7) ^ ((tid >> 3) & 7);
    const unsigned short* arp[4];
    const unsigned short* brp[4];
#pragma unroll
    for (int j = 0; j < 4; j++) {
        int row = j * 32 + rbase;
        int cl = row < mcnt ? row : mcnt - 1;
        arp[j] = h + (size_t)(m0 + cl) * K + kc * 8;
        brp[j] = bw + (size_t)(n0 + row) * K + kc * 8;
    }
    unsigned short* a_l = As + (wv << 6) * 8;
    unsigned short* b_l = Bs + (wv << 6) * 8;
    int fr = lane & 15, quad = lane >> 4, sw = fr & 7;
    int wm = (wv & 1) << 6, wn = (wv >> 1) << 6;
    f32x4 acc[4][4] = {};
    for (int k0 = 0; k0 < K; k0 += 64) {
        __syncthreads();
#pragma unroll
        for (int j = 0; j < 4; j++) {
            gll16(a_l + j * 2048, arp[j] + k0);
            gll16(b_l + j * 2048, brp[j] + k0);
        }
        __syncthreads();
#pragma unroll
        for (int s = 0; s < 2; s++) {
            int off = (((s << 2) + quad) ^ sw) << 3;
            bf16x8 a[4], b[4];
#pragma unroll
            for (int tm = 0; tm < 4; tm++)
                a[tm] = *(const bf16x8*)&As[(wm + tm * 16 + fr) * 64 + off];
#pragma unroll
            for (int tn = 0; tn < 4; tn++)
                b[tn] = *(const bf16x8*)&Bs[(wn + tn * 16 + fr) * 64 + off];
#pragma unroll
            for (int tm = 0; tm < 4; tm++)
#pragma unroll
                for (int tn = 0; tn < 4; tn++)
                    acc[tm][tn] = __builtin_amdgcn_mfma_f32_16x16x32_bf16(a[tm], b[tn], acc[tm][tn], 0, 0, 0);
        }
    }
#pragma unroll
    for (int tm = 0; tm < 4; tm++)
#pragma unroll
        for (int r = 0; r < 4; r++) {
            int row = wm + tm * 16 + (quad << 2) + r;
            if (row < mcnt) {
                if (GATHERED) {
                    int tok = at[m0 + row];
                    float w = awt[m0 + row];
#pragma unroll
                    for (int tn = 0; tn < 4; tn++)
                        atomicAdd(&out[(size_t)tok * DMODEL + n0 + wn + tn * 16 + fr],
                                  w * acc[tm][tn][r]);
                } else {
#pragma unroll
                    for (int tn = 0; tn < 4; tn++)
                        out[(size_t)(m0 + row) * DMODEL + n0 + wn + tn * 16 + fr] =
                            acc[tm][tn][r];
                }
            }
        }
}

// T1 generic transpose-convert (per-dispatch src/dst, z = expert)
__global__ __launch_bounds__(256) void k_tcvt(const float* __restrict__ src,
                                              unsigned short* __restrict__ dst,
                                              int K, int N) {
    src += (size_t)blockIdx.z * K * N;
    dst += (size_t)blockIdx.z * K * N;
    tcvt_tile(src, dst, N, K, blockIdx.x * 64, blockIdx.y * 64);
}

extern "C" void kernel_launch(void* const* d_in, const int* in_sizes, int n_in,
                              void* d_out, int out_size, void* d_ws, size_t ws_size,
                              hipStream_t stream) {
    (void)in_sizes; (void)n_in;
    const float* x  = (const float*)d_in[0];
    const float* rw = (const float*)d_in[1];
    const float* wg = (const float*)d_in[2];
    const float* wu = (const float*)d_in[3];
    const float* wd = (const float*)d_in[4];
    const float* sg = (const float*)d_in[5];
    const float* su = (const float*)d_in[6];
    const float* sd = (const float*)d_in[7];
    float* out = (float*)d_out;

    int* counts  = (int*)d_ws;
    int* offsets = counts + 8;
    int* cursors = counts + 16;
    int* ntiles  = counts + 24;
    int* tile_e  = counts + 32;          // 144
    int* tile_r  = tile_e + 144;         // 144
    int* topi    = tile_r + 144;         // 8192
    float* topw  = (float*)(topi + 8192);
    int* at      = (int*)(topw + 8192);
    float* aw    = (float*)(at + 8192);

    const size_t META = 262144;
    const size_t XB   = (size_t)NTOK * DMODEL * 2;              // 16,777,216
    unsigned short* xb = (unsigned short*)((char*)d_ws + META);

    const size_t FULL_NEED = 178520064;   // META+XB+poolW(115,343,360)+h_r+h_s
    const size_t FAST_NEED = 86245376;    // round-2 tier

    hipMemsetAsync(counts, 0, 32, stream);
    k_router2<<<dim3(512), 256, 0, stream>>>(x, rw, xb, topi, topw, counts);
    k_scan<<<1, 64, 0, stream>>>(counts, offsets, cursors, ntiles, tile_e, tile_r, 128);
    k_fill<<<dim3(NTOK / 256), 256, 0, stream>>>(topi, topw, cursors, at, aw);

    if (ws_size >= FULL_NEED) {
        char* pool = (char*)d_ws + META + XB;
        unsigned short* wgT = (unsigned short*)pool;                  // 46,137,344
        unsigned short* wuT = (unsigned short*)(pool + 46137344);     // 46,137,344
        unsigned short* sgT = (unsigned short*)(pool + 92274688);     // 11,534,336
        unsigned short* suT = (unsigned short*)(pool + 103809024);    // 11,534,336
        unsigned short* wdT = (unsigned short*)pool;                  // phase 2
        unsigned short* sdT = (unsigned short*)(pool + 46137344);     // phase 2
        unsigned short* h_r = (unsigned short*)(pool + 115343360);    // 23,068,672
        unsigned short* h_s = h_r + (size_t)8192 * HR;                // 23,068,672

        hipMemsetAsync(out, 0, (size_t)out_size * sizeof(float), stream);
        k_tcvt_gu<<<dim3(22, 32, 16), 256, 0, stream>>>(wg, wu, wgT, wuT);
        k_tcvt_s<<<dim3(44, 32, 2), 256, 0, stream>>>(sg, su, sgT, suT);
        kg_all<<<dim3(GU_SH_JOBS + MAXT128 * GU_RT_NB), 256, 0, stream>>>(
            xb, sgT, suT, wgT, wuT, tile_e, tile_r, offsets, counts, ntiles, at,
            h_s, h_r);
        k_tcvt_d<<<dim3(32, 22, 10), 256, 0, stream>>>(wd, sd, wdT, sdT);
        kd_all<<<dim3(DN_SH_JOBS + MAXT128 * 16), 256, 0, stream>>>(
            h_s, h_r, sdT, wdT, tile_e, tile_r, offsets, counts, ntiles, at, aw, out);
    } else {
        // T1: round-2 two-phase path (ws >= 86 MB proven in round 2)
        char* pool = (char*)d_ws + META + XB;
        unsigned short* sgT = (unsigned short*)pool;                  // 11,534,336
        unsigned short* suT = (unsigned short*)(pool + 11534336);     // 11,534,336
        unsigned short* h_s = (unsigned short*)(pool + 23068672);     // 23,068,672
        unsigned short* sdT = (unsigned short*)(pool + 46137344);     // 11,534,336
        unsigned short* wgT = (unsigned short*)pool;                  // 23,068,672 (4 exp)
        unsigned short* wuT = (unsigned short*)(pool + 23068672);     // 23,068,672 (4 exp)
        unsigned short* h_r = (unsigned short*)(pool + 46137344);     // 23,068,672
        unsigned short* wdT = (unsigned short*)pool;                  // 46,137,344 (8 exp)

        k_tcvt<<<dim3(HSHARED / 64, DMODEL / 64, 1), 256, 0, stream>>>(sg, sgT, DMODEL, HSHARED);
        k_tcvt<<<dim3(HSHARED / 64, DMODEL / 64, 1), 256, 0, stream>>>(su, suT, DMODEL, HSHARED);
        kf_gateup<false><<<dim3(NTOK / 128, HSHARED / 64), 256, 0, stream>>>(
            xb, sgT, suT, DMODEL, HSHARED, 0,
            nullptr, nullptr, nullptr, nullptr, nullptr, nullptr, h_s);
        k_tcvt<<<dim3(DMODEL / 64, HSHARED / 64, 1), 256, 0, stream>>>(sd, sdT, HSHARED, DMODEL);
        kf_down<false><<<dim3(NTOK / 128, DMODEL / 128), 256, 0, stream>>>(
            h_s, sdT, HSHARED,
            nullptr, nullptr, nullptr, nullptr, nullptr, nullptr, nullptr, out);
        k_tcvt<<<dim3(HR / 64, DMODEL / 64, 4), 256, 0, stream>>>(wg, wgT, DMODEL, HR);
        k_tcvt<<<dim3(HR / 64, DMODEL / 64, 4), 256, 0, stream>>>(wu, wuT, DMODEL, HR);
        kf_gateup<true><<<dim3(MAXT128, HR / 64), 256, 0, stream>>>(
            xb, wgT, wuT, DMODEL, HR, 0,
            tile_e, tile_r, offsets, counts, ntiles, at, h_r);
        k_tcvt<<<dim3(HR / 64, DMODEL / 64, 4), 256, 0, stream>>>(
            wg + (size_t)4 * DMODEL * HR, wgT, DMODEL, HR);
        k_tcvt<<<dim3(HR / 64, DMODEL / 64, 4), 256, 0, stream>>>(
            wu + (size_t)4 * DMODEL * HR, wuT, DMODEL, HR);
        kf_gateup<true><<<dim3(MAXT128, HR / 64), 256, 0, stream>>>(
            xb, wgT, wuT, DMODEL, HR, 4,
            tile_e, tile_r, offsets, counts, ntiles, at, h_r);
        k_tcvt<<<dim3(DMODEL / 64, HR / 64, 8), 256, 0, stream>>>(wd, wdT, HR, DMODEL);
        kf_down<true><<<dim3(MAXT128, DMODEL / 128), 256, 0, stream>>>(
            h_r, wdT, HR,
            tile_e, tile_r, offsets, counts, ntiles, at, aw, out);
    }
}